// Round 1
// baseline (120.614 us; speedup 1.0000x reference)
//
#include <hip/hip_runtime.h>
#include <hip/hip_bf16.h>
#include <math.h>

#define BB 32
#define NP 576
#define WW 32
#define DD 256

typedef __bf16 bf16x8 __attribute__((ext_vector_type(8)));
typedef float f32x4 __attribute__((ext_vector_type(4)));

__device__ __forceinline__ unsigned short f2bf(float f) {
  unsigned int u = __float_as_uint(f);
  u += 0x7FFFu + ((u >> 16) & 1u);
  return (unsigned short)(u >> 16);
}

// Kernel A: fused L2-normalize + bf16 cast. One wave (64 lanes) per row of 256 floats.
__global__ __launch_bounds__(256) void norm_cast_kernel(
    const float* __restrict__ img, const float* __restrict__ con,
    unsigned short* __restrict__ img_bf, unsigned short* __restrict__ con_bf) {
  int row = blockIdx.x * 4 + (threadIdx.x >> 6);
  int lane = threadIdx.x & 63;
  const int n_img = BB * NP;  // 18432 rows
  const float* src;
  unsigned short* dst;
  if (row < n_img) {
    src = img + (size_t)row * DD;
    dst = img_bf + (size_t)row * DD;
  } else {
    int r2 = row - n_img;
    src = con + (size_t)r2 * DD;
    dst = con_bf + (size_t)r2 * DD;
  }
  float4 v = ((const float4*)src)[lane];
  float ss = v.x * v.x + v.y * v.y + v.z * v.z + v.w * v.w;
  #pragma unroll
  for (int off = 1; off < 64; off <<= 1) ss += __shfl_xor(ss, off);
  float inv = 1.0f / fmaxf(sqrtf(ss), 1e-12f);  // matches F.normalize eps semantics
  ushort4 o;
  o.x = f2bf(v.x * inv);
  o.y = f2bf(v.y * inv);
  o.z = f2bf(v.z * inv);
  o.w = f2bf(v.w * inv);
  ((ushort4*)dst)[lane] = o;
}

// Kernel B: one block per (m,c) pair. Computes sim[m,c] = masked mean over w of
// max over n of cos(img[m,n], con[c,w]) via 16x16x32 bf16 MFMA.
// Fragment layouts (verified m89/m118):
//   A-frag: lane holds A[m = lane&15][k = (lane>>4)*8 + j], j=0..7 (contiguous)
//   B-frag: lane holds B^T[n = lane&15][k = (lane>>4)*8 + j]  (con is already [w][d])
//   D-frag: lane holds D[row = (lane>>4)*4 + r][col = lane&15]
__global__ __launch_bounds__(256) void pair_kernel(
    const unsigned short* __restrict__ img_bf,
    const unsigned short* __restrict__ con_bf,
    const int* __restrict__ lengths,
    float* __restrict__ sims) {
  int m = blockIdx.x >> 5;
  int c = blockIdx.x & 31;
  int wid = threadIdx.x >> 6;
  int lane = threadIdx.x & 63;
  int r = lane & 15;
  int q = lane >> 4;

  const unsigned short* Aimg = img_bf + (size_t)m * NP * DD;
  const unsigned short* Bcon = con_bf + (size_t)c * WW * DD;

  // Load all B fragments for both 16-concept tiles, all 8 K-steps: stays in VGPRs.
  bf16x8 bfrag[2][8];
  #pragma unroll
  for (int t = 0; t < 2; ++t) {
    #pragma unroll
    for (int kk = 0; kk < 8; ++kk) {
      uint4 raw = *(const uint4*)(Bcon + (size_t)(t * 16 + r) * DD + kk * 32 + q * 8);
      bfrag[t][kk] = __builtin_bit_cast(bf16x8, raw);
    }
  }

  float mx0 = -1e30f, mx1 = -1e30f;
  // 36 M-tiles of 16 patches; wave `wid` takes tiles wid, wid+4, ...
  for (int mt = wid; mt < 36; mt += 4) {
    const unsigned short* arow = Aimg + (size_t)(mt * 16 + r) * DD + q * 8;
    bf16x8 afrag[8];
    #pragma unroll
    for (int kk = 0; kk < 8; ++kk)
      afrag[kk] = __builtin_bit_cast(bf16x8, *(const uint4*)(arow + kk * 32));
    f32x4 acc0 = {0.f, 0.f, 0.f, 0.f};
    f32x4 acc1 = {0.f, 0.f, 0.f, 0.f};
    #pragma unroll
    for (int kk = 0; kk < 8; ++kk) {
      acc0 = __builtin_amdgcn_mfma_f32_16x16x32_bf16(afrag[kk], bfrag[0][kk], acc0, 0, 0, 0);
      acc1 = __builtin_amdgcn_mfma_f32_16x16x32_bf16(afrag[kk], bfrag[1][kk], acc1, 0, 0, 0);
    }
    mx0 = fmaxf(mx0, fmaxf(fmaxf(acc0[0], acc0[1]), fmaxf(acc0[2], acc0[3])));
    mx1 = fmaxf(mx1, fmaxf(fmaxf(acc1[0], acc1[1]), fmaxf(acc1[2], acc1[3])));
  }
  // Reduce max across the 4 row-quads (lanes sharing lane&15).
  mx0 = fmaxf(mx0, __shfl_xor(mx0, 16));
  mx0 = fmaxf(mx0, __shfl_xor(mx0, 32));
  mx1 = fmaxf(mx1, __shfl_xor(mx1, 16));
  mx1 = fmaxf(mx1, __shfl_xor(mx1, 32));

  __shared__ float smax[4][32];
  if (lane < 16) {
    smax[wid][lane] = mx0;
    smax[wid][lane + 16] = mx1;
  }
  __syncthreads();
  if (threadIdx.x < 32) {
    int w = threadIdx.x;
    float v = fmaxf(fmaxf(smax[0][w], smax[1][w]), fmaxf(smax[2][w], smax[3][w]));
    int len = lengths[c];
    float contrib = (w < len) ? v : 0.0f;
    #pragma unroll
    for (int off = 1; off < 32; off <<= 1) contrib += __shfl_xor(contrib, off);
    if (w == 0) sims[blockIdx.x] = contrib / (float)len;
  }
}

// Kernel C: fold 1024 sims into the SigLIP-style loss.
__global__ __launch_bounds__(256) void loss_kernel(
    const float* __restrict__ sims, const float* __restrict__ lscale,
    const float* __restrict__ lbias, float* __restrict__ out) {
  float t = expf(fminf(fmaxf(lscale[0], -10.0f), 10.0f));
  float bias = lbias[0];
  int tid = threadIdx.x;
  float acc = 0.0f;
  for (int p = tid; p < BB * BB; p += 256) {
    int m = p >> 5;
    int c = p & 31;
    float lg = fminf(fmaxf(t * sims[p] + bias, -50.0f), 50.0f);
    float x = (m == c) ? lg : -lg;  // z = +1 diag, -1 off-diag
    // stable log_sigmoid
    float ls = (x >= 0.0f) ? -log1pf(expf(-x)) : (x - log1pf(expf(x)));
    acc += ls;
  }
  #pragma unroll
  for (int off = 1; off < 64; off <<= 1) acc += __shfl_xor(acc, off);
  __shared__ float s[4];
  if ((tid & 63) == 0) s[tid >> 6] = acc;
  __syncthreads();
  if (tid == 0) out[0] = -(s[0] + s[1] + s[2] + s[3]) / (float)(BB * BB);
}

extern "C" void kernel_launch(void* const* d_in, const int* in_sizes, int n_in,
                              void* d_out, int out_size, void* d_ws, size_t ws_size,
                              hipStream_t stream) {
  const float* img = (const float*)d_in[0];     // (32, 576, 256) f32
  const float* con = (const float*)d_in[1];     // (32, 32, 256) f32
  const int* lens = (const int*)d_in[2];        // (32,) i32
  const float* lsc = (const float*)d_in[3];     // (1,)
  const float* lbi = (const float*)d_in[4];     // (1,)

  unsigned short* img_bf = (unsigned short*)d_ws;                 // 18432*256 bf16
  unsigned short* con_bf = img_bf + (size_t)BB * NP * DD;         // 1024*256 bf16
  float* sims = (float*)(con_bf + (size_t)BB * WW * DD);          // 1024 f32

  // 18432 + 1024 = 19456 rows, 4 rows per block (1 wave each)
  norm_cast_kernel<<<19456 / 4, 256, 0, stream>>>(img, con, img_bf, con_bf);
  pair_kernel<<<BB * BB, 256, 0, stream>>>(img_bf, con_bf, lens, sims);
  loss_kernel<<<1, 256, 0, stream>>>(sims, lsc, lbi, (float*)d_out);
}

// Round 2
// 96.659 us; speedup vs baseline: 1.2478x; 1.2478x over previous
//
#include <hip/hip_runtime.h>
#include <hip/hip_bf16.h>
#include <math.h>

#define BB 32
#define NP 576
#define WW 32
#define DD 256
// GEMM view: M = 32*576 = 18432, N = 32*32 = 1024, K = 256.
// M-tiles: 5 per image (4 full 128s + one 64-valid), N-tiles: 8 x 128.

typedef __bf16 bf16x8 __attribute__((ext_vector_type(8)));
typedef float f32x4 __attribute__((ext_vector_type(4)));

__device__ __forceinline__ unsigned short f2bf(float f) {
  unsigned int u = __float_as_uint(f);
  u += 0x7FFFu + ((u >> 16) & 1u);
  return (unsigned short)(u >> 16);
}

// Kernel A: fused L2-normalize + bf16 cast. One wave per row of 256 floats.
__global__ __launch_bounds__(256) void norm_cast_kernel(
    const float* __restrict__ img, const float* __restrict__ con,
    unsigned short* __restrict__ img_bf, unsigned short* __restrict__ con_bf) {
  int row = blockIdx.x * 4 + (threadIdx.x >> 6);
  int lane = threadIdx.x & 63;
  const int n_img = BB * NP;  // 18432 rows
  const float* src;
  unsigned short* dst;
  if (row < n_img) {
    src = img + (size_t)row * DD;
    dst = img_bf + (size_t)row * DD;
  } else {
    int r2 = row - n_img;
    src = con + (size_t)r2 * DD;
    dst = con_bf + (size_t)r2 * DD;
  }
  float4 v = ((const float4*)src)[lane];
  float ss = v.x * v.x + v.y * v.y + v.z * v.z + v.w * v.w;
  #pragma unroll
  for (int off = 1; off < 64; off <<= 1) ss += __shfl_xor(ss, off);
  float inv = 1.0f / fmaxf(sqrtf(ss), 1e-12f);
  ushort4 o;
  o.x = f2bf(v.x * inv);
  o.y = f2bf(v.y * inv);
  o.z = f2bf(v.z * inv);
  o.w = f2bf(v.w * inv);
  ((ushort4*)dst)[lane] = o;
}

// Kernel B: 128x128-tile GEMM (K=256, BK=64) with fused max-over-rows epilogue.
// Block (bm, bw): rows [p0, p0+128) of img (t==4 tile has only 64 valid rows),
// cols [w0, w0+128) of the 1024 concepts. Writes per-block partial max P[bm][wg].
// LDS layout: per 128-row tile, each row = 128 B (BK=64 bf16) stored as 8
// segments of 16 B, segment index XOR-swizzled by (row&7) -> conflict-free
// ds_write_b128 staging AND conflict-free ds_read_b128 fragment reads.
// Fragment layouts (same convention that passed in round 1):
//   A-frag: lane(q=lane>>4, r=lane&15) holds A[row=r][k=q*8+j]  (16B contiguous)
//   D-frag: lane holds D[row=q*4+reg][col=r]
__global__ __launch_bounds__(256, 3) void gemm_max_kernel(
    const unsigned short* __restrict__ img_bf,  // 18432 x 256
    const unsigned short* __restrict__ con_bf,  // 1024 x 256
    float* __restrict__ P) {                    // [160][1024] partial maxes
  int bx = blockIdx.x;
  int bw = bx & 7;    // N-tile 0..7
  int bm = bx >> 3;   // M-tile 0..159
  int m = bm / 5;
  int t = bm - m * 5;
  int p0 = m * NP + t * 128;  // global row base (t==4: rows 64..127 invalid)
  int w0 = bw * 128;

  __shared__ __align__(16) unsigned char lds[33 * 1024];
  unsigned char* ldsA = lds;            // 16 KB
  unsigned char* ldsB = lds + 16384;    // 16 KB
  float* sm = (float*)(lds + 32768);    // 2 x 128 floats

  int tid = threadIdx.x;
  int wid = tid >> 6;
  int lane = tid & 63;
  int q = lane >> 4;   // 0..3
  int r = lane & 15;   // 0..15
  int wp = wid >> 1;   // row-half 0..1 (64 rows each)
  int wc = wid & 1;    // col-half 0..1 (64 cols each)

  f32x4 acc[4][4];
  #pragma unroll
  for (int i = 0; i < 4; ++i)
    #pragma unroll
    for (int j = 0; j < 4; ++j) acc[i][j] = (f32x4){0.f, 0.f, 0.f, 0.f};

  for (int kb = 0; kb < 4; ++kb) {
    __syncthreads();
    // Stage A,B K-chunk: 16 KB each, 256 threads x 4 uint4 each side.
    uint4 va[4], vb[4];
    #pragma unroll
    for (int j = 0; j < 4; ++j) {
      int g = j * 256 + tid;       // 0..1023
      int row = g >> 3;            // 0..127
      int s = g & 7;               // 16B segment in the 128B row-chunk
      va[j] = *(const uint4*)(img_bf + (size_t)(p0 + row) * DD + kb * 64 + s * 8);
      vb[j] = *(const uint4*)(con_bf + (size_t)(w0 + row) * DD + kb * 64 + s * 8);
    }
    #pragma unroll
    for (int j = 0; j < 4; ++j) {
      int g = j * 256 + tid;
      int row = g >> 3;
      int s = g & 7;
      int sw = ((s ^ (row & 7)) << 4);
      *(uint4*)(ldsA + row * 128 + sw) = va[j];
      *(uint4*)(ldsB + row * 128 + sw) = vb[j];
    }
    __syncthreads();
    #pragma unroll
    for (int kk = 0; kk < 2; ++kk) {
      bf16x8 af[4], bfr[4];
      int sw = ((((kk << 2) | q) ^ (r & 7)) << 4);
      #pragma unroll
      for (int pi = 0; pi < 4; ++pi) {
        int arow = wp * 64 + pi * 16 + r;
        af[pi] = *(const bf16x8*)(ldsA + arow * 128 + sw);
      }
      #pragma unroll
      for (int wj = 0; wj < 4; ++wj) {
        int brow = wc * 64 + wj * 16 + r;
        bfr[wj] = *(const bf16x8*)(ldsB + brow * 128 + sw);
      }
      #pragma unroll
      for (int pi = 0; pi < 4; ++pi)
        #pragma unroll
        for (int wj = 0; wj < 4; ++wj)
          acc[pi][wj] =
              __builtin_amdgcn_mfma_f32_16x16x32_bf16(af[pi], bfr[wj], acc[pi][wj], 0, 0, 0);
    }
  }

  // Epilogue: max over this wave's 64 rows for each of its 64 cols.
  float mxw[4];
  #pragma unroll
  for (int wj = 0; wj < 4; ++wj) {
    float v = -1e30f;
    #pragma unroll
    for (int pi = 0; pi < 4; ++pi) {
      v = fmaxf(v, fmaxf(fmaxf(acc[pi][wj][0], acc[pi][wj][1]),
                         fmaxf(acc[pi][wj][2], acc[pi][wj][3])));
    }
    v = fmaxf(v, __shfl_xor(v, 16));
    v = fmaxf(v, __shfl_xor(v, 32));
    mxw[wj] = v;
  }
  __syncthreads();
  if (lane < 16) {
    #pragma unroll
    for (int wj = 0; wj < 4; ++wj)
      sm[wp * 128 + wc * 64 + wj * 16 + lane] = mxw[wj];
  }
  __syncthreads();
  if (tid < 128) {
    float v = sm[tid];                       // rows 0..63 (always valid)
    if (t != 4) v = fmaxf(v, sm[128 + tid]); // rows 64..127 only if valid
    P[(size_t)bm * 1024 + w0 + tid] = v;
  }
}

// Kernel C: reduce partial maxes over the 5 M-tiles of each image, then
// masked mean over valid concepts -> sims[m*32+c].
__global__ __launch_bounds__(256) void reduce_kernel(
    const float* __restrict__ P, const int* __restrict__ lengths,
    float* __restrict__ sims) {
  int pair = blockIdx.x * 4 + (threadIdx.x >> 6);  // 0..1023
  int lane = threadIdx.x & 63;
  int m = pair >> 5;
  int c = pair & 31;
  int w = lane & 31;
  const float* base = P + (size_t)(m * 5) * 1024 + c * 32 + w;
  float v = base[0];
  v = fmaxf(v, base[1024]);
  v = fmaxf(v, base[2048]);
  v = fmaxf(v, base[3072]);
  v = fmaxf(v, base[4096]);
  int len = lengths[c];
  float contrib = (w < len) ? v : 0.0f;
  #pragma unroll
  for (int off = 1; off < 32; off <<= 1) contrib += __shfl_xor(contrib, off);
  if (lane == 0) sims[pair] = contrib / (float)len;
}

// Kernel D: fold 1024 sims into the SigLIP-style loss.
__global__ __launch_bounds__(256) void loss_kernel(
    const float* __restrict__ sims, const float* __restrict__ lscale,
    const float* __restrict__ lbias, float* __restrict__ out) {
  float tt = expf(fminf(fmaxf(lscale[0], -10.0f), 10.0f));
  float bias = lbias[0];
  int tid = threadIdx.x;
  float acc = 0.0f;
  for (int p = tid; p < BB * BB; p += 256) {
    int mm = p >> 5;
    int cc = p & 31;
    float lg = fminf(fmaxf(tt * sims[p] + bias, -50.0f), 50.0f);
    float x = (mm == cc) ? lg : -lg;
    float ls = (x >= 0.0f) ? -log1pf(expf(-x)) : (x - log1pf(expf(x)));
    acc += ls;
  }
  #pragma unroll
  for (int off = 1; off < 64; off <<= 1) acc += __shfl_xor(acc, off);
  __shared__ float s[4];
  if ((tid & 63) == 0) s[tid >> 6] = acc;
  __syncthreads();
  if (tid == 0) out[0] = -(s[0] + s[1] + s[2] + s[3]) / (float)(BB * BB);
}

extern "C" void kernel_launch(void* const* d_in, const int* in_sizes, int n_in,
                              void* d_out, int out_size, void* d_ws, size_t ws_size,
                              hipStream_t stream) {
  const float* img = (const float*)d_in[0];  // (32, 576, 256) f32
  const float* con = (const float*)d_in[1];  // (32, 32, 256) f32
  const int* lens = (const int*)d_in[2];     // (32,) i32
  const float* lsc = (const float*)d_in[3];  // (1,)
  const float* lbi = (const float*)d_in[4];  // (1,)

  unsigned short* img_bf = (unsigned short*)d_ws;              // 18432*256 bf16
  unsigned short* con_bf = img_bf + (size_t)BB * NP * DD;      // 1024*256 bf16
  float* P = (float*)(con_bf + (size_t)BB * WW * DD);          // 160*1024 f32
  float* sims = P + (size_t)160 * 1024;                        // 1024 f32

  norm_cast_kernel<<<(BB * NP + BB * WW) / 4, 256, 0, stream>>>(img, con, img_bf, con_bf);
  gemm_max_kernel<<<160 * 8, 256, 0, stream>>>(img_bf, con_bf, P);
  reduce_kernel<<<256, 256, 0, stream>>>(P, lens, sims);
  loss_kernel<<<1, 256, 0, stream>>>(sims, lsc, lbi, (float*)d_out);
}